// Round 13
// baseline (320.491 us; speedup 1.0000x reference)
//
#include <hip/hip_runtime.h>
#include <hip/hip_bf16.h>

#define NN 100000
#define NE 1600000
#define D  128
#define NB 98            // dst buckets of 1024 nodes (dst>>10)
#define BSLOT 18432      // fixed slots per bucket region (mean 16384 + 16 sigma)
#define BCHUNK 8192      // edges per binning block

typedef short bf16x8 __attribute__((ext_vector_type(8)));
typedef float f32x4 __attribute__((ext_vector_type(4)));

static __device__ inline unsigned short f2b(float f) {
    __hip_bfloat16 b = __float2bfloat16(f);   // RNE
    unsigned short u;
    __builtin_memcpy(&u, &b, 2);
    return u;
}

// init per-bucket cursors to fixed region starts (self-sizing buckets:
// no count pass, no scan)
__global__ void init_gcur(int* __restrict__ gcur) {
    int t = threadIdx.x;
    if (t < NB) gcur[t] = t * BSLOT;
}

// bin edges by dst>>10 into packed 4B entries: (dstLocal10<<17) | src17.
// Regions are pre-sized; LDS histogram batches the per-bucket reservation.
__global__ __launch_bounds__(256) void bin_scatter(const int* __restrict__ ei,
                                                   int* __restrict__ gcur,
                                                   unsigned* __restrict__ ebuf) {
    __shared__ int hist[NB];
    __shared__ int base_s[NB];
    int chunk0 = blockIdx.x * BCHUNK;
    for (int t = threadIdx.x; t < NB; t += 256) hist[t] = 0;
    __syncthreads();
    for (int i = 0; i < BCHUNK; i += 256) {
        int e = chunk0 + i + threadIdx.x;
        if (e < NE) atomicAdd(&hist[ei[NE + e] >> 10], 1);
    }
    __syncthreads();
    for (int t = threadIdx.x; t < NB; t += 256) {
        base_s[t] = hist[t] ? atomicAdd(&gcur[t], hist[t]) : 0;
        hist[t] = 0;
    }
    __syncthreads();
    for (int i = 0; i < BCHUNK; i += 256) {
        int e = chunk0 + i + threadIdx.x;
        if (e < NE) {
            int s = ei[e];
            int d = ei[NE + e];
            int b = d >> 10;
            int off = atomicAdd(&hist[b], 1);
            ebuf[(size_t)base_s[b] + off] = ((unsigned)(d & 1023) << 17) | (unsigned)s;
        }
    }
}

// One block per 1024-node bucket: per-node counts (native LDS int atomics),
// 1024-wide LDS scan -> rowbeg/rowend (gapped CSR), then scatter col through
// LDS cursors. Bucket's col window owned by ONE block on ONE XCD (r11 lesson).
__global__ __launch_bounds__(1024) void sort_bucket(
    const unsigned* __restrict__ ebuf, const int* __restrict__ gcur,
    int* __restrict__ rowbeg, int* __restrict__ rowend, int* __restrict__ col)
{
    __shared__ int cnt[1024];
    __shared__ int tmp[1024];
    __shared__ int cur[1024];
    const int b = blockIdx.x;
    const int t = threadIdx.x;
    const int beg = b * BSLOT;
    const int end = gcur[b];
    const int node0 = b << 10;

    cnt[t] = 0;
    __syncthreads();
    for (int j = beg + t; j < end; j += 1024)
        atomicAdd(&cnt[ebuf[j] >> 17], 1);
    __syncthreads();

    int v = cnt[t];
    tmp[t] = v;
    __syncthreads();
    for (int off = 1; off < 1024; off <<= 1) {
        int tv = (t >= off) ? tmp[t - off] : 0;
        __syncthreads();
        tmp[t] += tv;
        __syncthreads();
    }
    int gpos = beg + (tmp[t] - v);
    if (node0 + t < NN) { rowbeg[node0 + t] = gpos; rowend[node0 + t] = gpos + v; }
    cur[t] = gpos;
    __syncthreads();

    for (int j = beg + t; j < end; j += 1024) {
        unsigned p = ebuf[j];
        int pos = atomicAdd(&cur[p >> 17], 1);
        col[pos] = (int)(p & 0x1ffffu);
    }
}

// fp32 -> bf16 conversion, 4 elems/thread
__global__ void conv_f2b(const float* __restrict__ src,
                         unsigned short* __restrict__ dst, int n) {
    int i = (blockIdx.x * 256 + threadIdx.x) * 4;
    if (i + 3 < n) {
        float4 v = *(const float4*)(src + i);
        ushort4 o;
        o.x = f2b(v.x); o.y = f2b(v.y); o.z = f2b(v.z); o.w = f2b(v.w);
        *(ushort4*)(dst + i) = o;
    } else {
        for (; i < n; ++i) dst[i] = f2b(src[i]);
    }
}

// all 4 weight matrices (each D*D) in one launch; dsts contiguous
__global__ void conv_w4(const float* __restrict__ s0, const float* __restrict__ s1,
                        const float* __restrict__ s2, const float* __restrict__ s3,
                        unsigned short* __restrict__ dst) {
    int i = (blockIdx.x * 256 + threadIdx.x) * 4;   // [0, 4*D*D)
    const float* srcs[4] = {s0, s1, s2, s3};
    const float* s = srcs[i >> 14];                 // D*D = 16384
    float4 v = *(const float4*)(s + (i & 16383));
    ushort4 o;
    o.x = f2b(v.x); o.y = f2b(v.y); o.z = f2b(v.z); o.w = f2b(v.w);
    *(ushort4*)(dst + i) = o;
}

// Fused SAGE layer: block = 64 nodes, 4 waves.
// Phase 1: each wave mean-aggregates 16 nodes (round-8 proven gather inner
//          loop: two 32-lane halves, uint2/lane, 8 edges in flight), packs
//          bf16 agg rows into LDS sA.
// Phase 2: MFMA 16x16x32 tile (round-11): A from sA, H fragments direct from
//          global (64 rows x 256B = 16KB, L1-resident), W from global (L2-hot).
// launch_bounds(256,6): >=24 waves/CU so the gather phase keeps its latency
// hiding (unfused aggregate ran at ~69% occ = 22 waves).
template <int OUT_F32>
__global__ __launch_bounds__(256, 6) void fused_sage(
    const unsigned short* __restrict__ Hb,   // input features [NN][128] bf16
    const int* __restrict__ rowbeg, const int* __restrict__ rowend,
    const int* __restrict__ col,
    const unsigned short* __restrict__ Wlb,  // [128][128], row j contiguous in k
    const unsigned short* __restrict__ Wrb,
    const float* __restrict__ bias,
    float* __restrict__ outf,
    unsigned short* __restrict__ outb)
{
    __shared__ unsigned short sA[64][136];   // 17.4 KB (272B-padded rows)
    const int tid = threadIdx.x;
    const int block0 = blockIdx.x * 64;
    const int lane = tid & 63;
    const int wid  = tid >> 6;
    const int half = lane >> 5;
    const int sl   = lane & 31;
    const uint2* hp = (const uint2*)Hb;   // 32 uint2 per row

    // ---- phase 1: gather + mean for this wave's 16 nodes ----
    for (int i = 0; i < 16; ++i) {
        const int node = block0 + wid * 16 + i;
        float a0 = 0.f, a1 = 0.f, a2 = 0.f, a3 = 0.f;
        int beg = 0, end = 0;
        if (node < NN) { beg = rowbeg[node]; end = rowend[node]; }

        int j = beg + half;
        for (; j + 6 < end; j += 8) {
            int c0 = col[j];
            int c1 = col[j + 2];
            int c2 = col[j + 4];
            int c3 = col[j + 6];
            uint2 v0 = hp[c0 * 32 + sl];
            uint2 v1 = hp[c1 * 32 + sl];
            uint2 v2 = hp[c2 * 32 + sl];
            uint2 v3 = hp[c3 * 32 + sl];
            a0 += __uint_as_float(v0.x << 16) + __uint_as_float(v1.x << 16)
                + __uint_as_float(v2.x << 16) + __uint_as_float(v3.x << 16);
            a1 += __uint_as_float(v0.x & 0xffff0000u) + __uint_as_float(v1.x & 0xffff0000u)
                + __uint_as_float(v2.x & 0xffff0000u) + __uint_as_float(v3.x & 0xffff0000u);
            a2 += __uint_as_float(v0.y << 16) + __uint_as_float(v1.y << 16)
                + __uint_as_float(v2.y << 16) + __uint_as_float(v3.y << 16);
            a3 += __uint_as_float(v0.y & 0xffff0000u) + __uint_as_float(v1.y & 0xffff0000u)
                + __uint_as_float(v2.y & 0xffff0000u) + __uint_as_float(v3.y & 0xffff0000u);
        }
        for (; j < end; j += 2) {
            uint2 v = hp[col[j] * 32 + sl];
            a0 += __uint_as_float(v.x << 16);
            a1 += __uint_as_float(v.x & 0xffff0000u);
            a2 += __uint_as_float(v.y << 16);
            a3 += __uint_as_float(v.y & 0xffff0000u);
        }

        a0 += __shfl_xor(a0, 32);
        a1 += __shfl_xor(a1, 32);
        a2 += __shfl_xor(a2, 32);
        a3 += __shfl_xor(a3, 32);

        int deg = end - beg;
        float inv = 1.0f / (float)(deg > 1 ? deg : 1);
        if (half == 0) {
            uint2 o;
            o.x = (unsigned)f2b(a0 * inv) | ((unsigned)f2b(a1 * inv) << 16);
            o.y = (unsigned)f2b(a2 * inv) | ((unsigned)f2b(a3 * inv) << 16);
            *(uint2*)(&sA[wid * 16 + i][sl * 4]) = o;
        }
    }
    __syncthreads();

    // ---- phase 2: out = leaky( A@Wl^T + H@Wr^T + b ) ----
    const int r  = lane & 15;
    const int kg = lane >> 4;
    const int rbase = (wid >> 1) * 32;     // 0 or 32
    const int col0  = (wid & 1) * 64;
    const int ga0 = min(block0 + rbase + r,      NN - 1);
    const int ga1 = min(block0 + rbase + 16 + r, NN - 1);

    float bv[4];
#pragma unroll
    for (int c = 0; c < 4; ++c) bv[c] = bias[col0 + c * 16 + r];

    f32x4 acc[2][4];
#pragma unroll
    for (int m = 0; m < 2; ++m)
#pragma unroll
        for (int c = 0; c < 4; ++c) acc[m][c] = (f32x4){0.f, 0.f, 0.f, 0.f};

#pragma unroll
    for (int ks = 0; ks < 8; ++ks) {
        const int kk = (ks & 3) * 32 + kg * 8;
        bf16x8 a0, a1;
        if (ks < 4) {
            a0 = *(const bf16x8*)(&sA[rbase + r][kk]);
            a1 = *(const bf16x8*)(&sA[rbase + 16 + r][kk]);
        } else {
            a0 = *(const bf16x8*)(Hb + (size_t)ga0 * D + kk);
            a1 = *(const bf16x8*)(Hb + (size_t)ga1 * D + kk);
        }
        const unsigned short* W = (ks < 4) ? Wlb : Wrb;
        bf16x8 bw[4];
#pragma unroll
        for (int c = 0; c < 4; ++c)
            bw[c] = *(const bf16x8*)(W + (size_t)(col0 + c * 16 + r) * D + kk);
#pragma unroll
        for (int c = 0; c < 4; ++c) {
            acc[0][c] = __builtin_amdgcn_mfma_f32_16x16x32_bf16(a0, bw[c], acc[0][c], 0, 0, 0);
            acc[1][c] = __builtin_amdgcn_mfma_f32_16x16x32_bf16(a1, bw[c], acc[1][c], 0, 0, 0);
        }
    }

    // C/D layout: col = c*16 + (lane&15), row = m*16 + (lane>>4)*4 + q   [m89]
#pragma unroll
    for (int m = 0; m < 2; ++m) {
#pragma unroll
        for (int q = 0; q < 4; ++q) {
            int row = block0 + rbase + m * 16 + kg * 4 + q;
            if (row < NN) {
#pragma unroll
                for (int c = 0; c < 4; ++c) {
                    float v = acc[m][c][q] + bv[c];
                    v = v > 0.f ? v : 0.5f * v;
                    int colj = col0 + c * 16 + r;
                    if (OUT_F32) outf[(size_t)row * D + colj] = v;
                    else         outb[(size_t)row * D + colj] = f2b(v);
                }
            }
        }
    }
}

extern "C" void kernel_launch(void* const* d_in, const int* in_sizes, int n_in,
                              void* d_out, int out_size, void* d_ws, size_t ws_size,
                              hipStream_t stream) {
    const float* x   = (const float*)d_in[0];
    const int*   ei  = (const int*)d_in[1];
    const float* W1l = (const float*)d_in[2];
    const float* W1r = (const float*)d_in[3];
    const float* b1  = (const float*)d_in[4];
    const float* W2l = (const float*)d_in[5];
    const float* W2r = (const float*)d_in[6];
    const float* b2  = (const float*)d_in[7];
    float* out = (float*)d_out;

    char* ws = (char*)d_ws;
    size_t off = 0;
    auto alloc = [&](size_t bytes) {
        void* p = ws + off;
        off = (off + bytes + 255) & ~(size_t)255;
        return p;
    };
    int* rowbeg = (int*)alloc((size_t)NN * 4);
    int* rowend = (int*)alloc((size_t)NN * 4);
    int* gcur   = (int*)alloc((NB + 1) * 4);
    int* col    = (int*)alloc((size_t)NB * BSLOT * 4);   // gapped CSR
    unsigned short* xb  = (unsigned short*)alloc((size_t)NN * D * 2);
    unsigned short* h1b = (unsigned short*)alloc((size_t)NN * D * 2);
    unsigned short* wb  = (unsigned short*)alloc((size_t)4 * D * D * 2);
    unsigned short* w1lb = wb;
    unsigned short* w1rb = wb + D * D;
    unsigned short* w2lb = wb + 2 * D * D;
    unsigned short* w2rb = wb + 3 * D * D;
    // ebuf (7.2 MB) aliases h1b (25.6 MB): ebuf dead before h1b is written
    unsigned* ebuf = (unsigned*)h1b;

    // ---- CSR build: self-sizing bucket regions, one sort block per bucket ----
    init_gcur<<<1, 128, 0, stream>>>(gcur);
    bin_scatter<<<(NE + BCHUNK - 1) / BCHUNK, 256, 0, stream>>>(ei, gcur, ebuf);
    sort_bucket<<<NB, 1024, 0, stream>>>(ebuf, gcur, rowbeg, rowend, col);

    // ---- bf16 conversions ----
    conv_f2b<<<(NN * D / 4 + 255) / 256, 256, 0, stream>>>(x, xb, NN * D);
    conv_w4<<<(4 * D * D / 4 + 255) / 256, 256, 0, stream>>>(W1l, W1r, W2l, W2r, wb);

    // ---- fused layers: gather+mean -> MFMA -> leaky ----
    fused_sage<0><<<(NN + 63) / 64, 256, 0, stream>>>(xb, rowbeg, rowend, col,
                                                      w1lb, w1rb, b1, nullptr, h1b);
    fused_sage<1><<<(NN + 63) / 64, 256, 0, stream>>>(h1b, rowbeg, rowend, col,
                                                      w2lb, w2rb, b2, out, nullptr);
}

// Round 14
// 266.343 us; speedup vs baseline: 1.2033x; 1.2033x over previous
//
#include <hip/hip_runtime.h>
#include <hip/hip_bf16.h>

#define NN 100000
#define NE 1600000
#define D  128
#define NB 98            // dst buckets of 1024 nodes (dst>>10)
#define BSLOT 18432      // fixed slots per bucket region (mean 16384 + 16 sigma)
#define BCHUNK 8192      // edges per binning block

typedef short bf16x8 __attribute__((ext_vector_type(8)));
typedef float f32x4 __attribute__((ext_vector_type(4)));

static __device__ inline unsigned short f2b(float f) {
    __hip_bfloat16 b = __float2bfloat16(f);   // RNE
    unsigned short u;
    __builtin_memcpy(&u, &b, 2);
    return u;
}

// init per-bucket cursors to fixed region starts (self-sizing buckets:
// no count pass, no scan)
__global__ void init_gcur(int* __restrict__ gcur) {
    int t = threadIdx.x;
    if (t < NB) gcur[t] = t * BSLOT;
}

// bin edges by dst>>10 into packed 4B entries: (dstLocal10<<17) | src17.
// Regions are pre-sized; LDS histogram batches the per-bucket reservation.
__global__ __launch_bounds__(256) void bin_scatter(const int* __restrict__ ei,
                                                   int* __restrict__ gcur,
                                                   unsigned* __restrict__ ebuf) {
    __shared__ int hist[NB];
    __shared__ int base_s[NB];
    int chunk0 = blockIdx.x * BCHUNK;
    for (int t = threadIdx.x; t < NB; t += 256) hist[t] = 0;
    __syncthreads();
    for (int i = 0; i < BCHUNK; i += 256) {
        int e = chunk0 + i + threadIdx.x;
        if (e < NE) atomicAdd(&hist[ei[NE + e] >> 10], 1);
    }
    __syncthreads();
    for (int t = threadIdx.x; t < NB; t += 256) {
        base_s[t] = hist[t] ? atomicAdd(&gcur[t], hist[t]) : 0;
        hist[t] = 0;
    }
    __syncthreads();
    for (int i = 0; i < BCHUNK; i += 256) {
        int e = chunk0 + i + threadIdx.x;
        if (e < NE) {
            int s = ei[e];
            int d = ei[NE + e];
            int b = d >> 10;
            int off = atomicAdd(&hist[b], 1);
            ebuf[(size_t)base_s[b] + off] = ((unsigned)(d & 1023) << 17) | (unsigned)s;
        }
    }
}

// One block per 1024-node bucket: per-node counts (native LDS int atomics),
// 1024-wide LDS scan -> rowbeg/rowend (gapped CSR), then scatter col through
// LDS cursors. Bucket's col window owned by ONE block on ONE XCD (r11 lesson).
__global__ __launch_bounds__(1024) void sort_bucket(
    const unsigned* __restrict__ ebuf, const int* __restrict__ gcur,
    int* __restrict__ rowbeg, int* __restrict__ rowend, int* __restrict__ col)
{
    __shared__ int cnt[1024];
    __shared__ int tmp[1024];
    __shared__ int cur[1024];
    const int b = blockIdx.x;
    const int t = threadIdx.x;
    const int beg = b * BSLOT;
    const int end = gcur[b];
    const int node0 = b << 10;

    cnt[t] = 0;
    __syncthreads();
    for (int j = beg + t; j < end; j += 1024)
        atomicAdd(&cnt[ebuf[j] >> 17], 1);
    __syncthreads();

    int v = cnt[t];
    tmp[t] = v;
    __syncthreads();
    for (int off = 1; off < 1024; off <<= 1) {
        int tv = (t >= off) ? tmp[t - off] : 0;
        __syncthreads();
        tmp[t] += tv;
        __syncthreads();
    }
    int gpos = beg + (tmp[t] - v);
    if (node0 + t < NN) { rowbeg[node0 + t] = gpos; rowend[node0 + t] = gpos + v; }
    cur[t] = gpos;
    __syncthreads();

    for (int j = beg + t; j < end; j += 1024) {
        unsigned p = ebuf[j];
        int pos = atomicAdd(&cur[p >> 17], 1);
        col[pos] = (int)(p & 0x1ffffu);
    }
}

// fp32 -> bf16 conversion, 4 elems/thread
__global__ void conv_f2b(const float* __restrict__ src,
                         unsigned short* __restrict__ dst, int n) {
    int i = (blockIdx.x * 256 + threadIdx.x) * 4;
    if (i + 3 < n) {
        float4 v = *(const float4*)(src + i);
        ushort4 o;
        o.x = f2b(v.x); o.y = f2b(v.y); o.z = f2b(v.z); o.w = f2b(v.w);
        *(ushort4*)(dst + i) = o;
    } else {
        for (; i < n; ++i) dst[i] = f2b(src[i]);
    }
}

// all 4 weight matrices (each D*D) in one launch; dsts contiguous
__global__ void conv_w4(const float* __restrict__ s0, const float* __restrict__ s1,
                        const float* __restrict__ s2, const float* __restrict__ s3,
                        unsigned short* __restrict__ dst) {
    int i = (blockIdx.x * 256 + threadIdx.x) * 4;   // [0, 4*D*D)
    const float* srcs[4] = {s0, s1, s2, s3};
    const float* s = srcs[i >> 14];                 // D*D = 16384
    float4 v = *(const float4*)(s + (i & 16383));
    ushort4 o;
    o.x = f2b(v.x); o.y = f2b(v.y); o.z = f2b(v.z); o.w = f2b(v.w);
    *(ushort4*)(dst + i) = o;
}

// mean aggregation over bf16 features; two 32-lane halves per wave, uint2/lane
// (round-8 proven gather: 62 us, 3.3 TB/s, FETCH at the coverage floor;
// standalone kernel on purpose — r13 showed fusing it with the GEMM costs
// occupancy and 35% perf)
__global__ __launch_bounds__(256) void aggregate(const unsigned short* __restrict__ hb,
                                                 const int* __restrict__ rowbeg,
                                                 const int* __restrict__ rowend,
                                                 const int* __restrict__ col,
                                                 unsigned short* __restrict__ aggb) {
    int node = blockIdx.x * 4 + (threadIdx.x >> 6);
    if (node >= NN) return;
    int lane = threadIdx.x & 63;
    int half = lane >> 5;
    int sl   = lane & 31;
    int beg = rowbeg[node], end = rowend[node];
    const uint2* hp = (const uint2*)hb;   // 32 uint2 per row
    float a0 = 0.f, a1 = 0.f, a2 = 0.f, a3 = 0.f;

    int j = beg + half;
    for (; j + 6 < end; j += 8) {
        int c0 = col[j];
        int c1 = col[j + 2];
        int c2 = col[j + 4];
        int c3 = col[j + 6];
        uint2 v0 = hp[c0 * 32 + sl];
        uint2 v1 = hp[c1 * 32 + sl];
        uint2 v2 = hp[c2 * 32 + sl];
        uint2 v3 = hp[c3 * 32 + sl];
        a0 += __uint_as_float(v0.x << 16) + __uint_as_float(v1.x << 16)
            + __uint_as_float(v2.x << 16) + __uint_as_float(v3.x << 16);
        a1 += __uint_as_float(v0.x & 0xffff0000u) + __uint_as_float(v1.x & 0xffff0000u)
            + __uint_as_float(v2.x & 0xffff0000u) + __uint_as_float(v3.x & 0xffff0000u);
        a2 += __uint_as_float(v0.y << 16) + __uint_as_float(v1.y << 16)
            + __uint_as_float(v2.y << 16) + __uint_as_float(v3.y << 16);
        a3 += __uint_as_float(v0.y & 0xffff0000u) + __uint_as_float(v1.y & 0xffff0000u)
            + __uint_as_float(v2.y & 0xffff0000u) + __uint_as_float(v3.y & 0xffff0000u);
    }
    for (; j < end; j += 2) {
        uint2 v = hp[col[j] * 32 + sl];
        a0 += __uint_as_float(v.x << 16);
        a1 += __uint_as_float(v.x & 0xffff0000u);
        a2 += __uint_as_float(v.y << 16);
        a3 += __uint_as_float(v.y & 0xffff0000u);
    }

    a0 += __shfl_xor(a0, 32);
    a1 += __shfl_xor(a1, 32);
    a2 += __shfl_xor(a2, 32);
    a3 += __shfl_xor(a3, 32);

    int deg = end - beg;
    float inv = 1.0f / (float)(deg > 1 ? deg : 1);
    if (half == 0) {
        uint2 o;
        o.x = (unsigned)f2b(a0 * inv) | ((unsigned)f2b(a1 * inv) << 16);
        o.y = (unsigned)f2b(a2 * inv) | ((unsigned)f2b(a3 * inv) << 16);
        ((uint2*)aggb)[(size_t)node * 32 + sl] = o;
    }
}

// out[n][j] = leaky_relu( sum_k agg[n][k]*Wl[j][k] + h[n][k]*Wr[j][k] + b[j], 0.5 )
// MFMA 16x16x32 bf16. Block = 256 thr = 4 waves (2x2), tile 64 rows x 128 cols.
// A/H slabs staged via coalesced uint4 loads into 272B-padded LDS rows.
template <int OUT_F32>
__global__ __launch_bounds__(256) void sage_gemm_mfma(
    const unsigned short* __restrict__ Ab,   // [NN][128] aggregated
    const unsigned short* __restrict__ Hb,   // [NN][128] root
    const unsigned short* __restrict__ Wlb,  // [128][128], row j contiguous in k
    const unsigned short* __restrict__ Wrb,
    const float* __restrict__ bias,
    float* __restrict__ outf,
    unsigned short* __restrict__ outb)
{
    __shared__ unsigned short sA[64][136];   // 17.4 KB (272B rows)
    __shared__ unsigned short sH[64][136];
    const int tid = threadIdx.x;
    const int block0 = blockIdx.x * 64;

    {
        int i = tid;   // 64 rows x 16 quads = 1024; 4 iters of 256 threads
#pragma unroll
        for (int k = 0; k < 4; ++k, i += 256) {
            int row = i >> 4, c16 = i & 15;
            int grow = block0 + row; if (grow >= NN) grow = NN - 1;
            *(uint4*)(&sA[row][c16 * 8]) = *(const uint4*)(Ab + (size_t)grow * D + c16 * 8);
            *(uint4*)(&sH[row][c16 * 8]) = *(const uint4*)(Hb + (size_t)grow * D + c16 * 8);
        }
    }
    __syncthreads();

    const int lane = tid & 63;
    const int wid  = tid >> 6;
    const int r  = lane & 15;
    const int kg = lane >> 4;
    const int rbase = (wid >> 1) * 32;     // 0 or 32
    const int col0  = (wid & 1) * 64;

    float bv[4];
#pragma unroll
    for (int c = 0; c < 4; ++c) bv[c] = bias[col0 + c * 16 + r];

    f32x4 acc[2][4];
#pragma unroll
    for (int m = 0; m < 2; ++m)
#pragma unroll
        for (int c = 0; c < 4; ++c) acc[m][c] = (f32x4){0.f, 0.f, 0.f, 0.f};

#pragma unroll
    for (int ks = 0; ks < 8; ++ks) {
        const unsigned short (*S)[136] = (ks < 4) ? sA : sH;
        const unsigned short* W = (ks < 4) ? Wlb : Wrb;
        const int kk = (ks & 3) * 32 + kg * 8;
        bf16x8 a0 = *(const bf16x8*)(&S[rbase + r][kk]);
        bf16x8 a1 = *(const bf16x8*)(&S[rbase + 16 + r][kk]);
        bf16x8 bw[4];
#pragma unroll
        for (int c = 0; c < 4; ++c)
            bw[c] = *(const bf16x8*)(W + (size_t)(col0 + c * 16 + r) * D + kk);
#pragma unroll
        for (int c = 0; c < 4; ++c) {
            acc[0][c] = __builtin_amdgcn_mfma_f32_16x16x32_bf16(a0, bw[c], acc[0][c], 0, 0, 0);
            acc[1][c] = __builtin_amdgcn_mfma_f32_16x16x32_bf16(a1, bw[c], acc[1][c], 0, 0, 0);
        }
    }

    // C/D layout: col = c*16 + (lane&15), row = m*16 + (lane>>4)*4 + q   [m89]
#pragma unroll
    for (int m = 0; m < 2; ++m) {
#pragma unroll
        for (int q = 0; q < 4; ++q) {
            int row = block0 + rbase + m * 16 + kg * 4 + q;
            if (row < NN) {
#pragma unroll
                for (int c = 0; c < 4; ++c) {
                    float v = acc[m][c][q] + bv[c];
                    v = v > 0.f ? v : 0.5f * v;
                    int colj = col0 + c * 16 + r;
                    if (OUT_F32) outf[(size_t)row * D + colj] = v;
                    else         outb[(size_t)row * D + colj] = f2b(v);
                }
            }
        }
    }
}

extern "C" void kernel_launch(void* const* d_in, const int* in_sizes, int n_in,
                              void* d_out, int out_size, void* d_ws, size_t ws_size,
                              hipStream_t stream) {
    const float* x   = (const float*)d_in[0];
    const int*   ei  = (const int*)d_in[1];
    const float* W1l = (const float*)d_in[2];
    const float* W1r = (const float*)d_in[3];
    const float* b1  = (const float*)d_in[4];
    const float* W2l = (const float*)d_in[5];
    const float* W2r = (const float*)d_in[6];
    const float* b2  = (const float*)d_in[7];
    float* out = (float*)d_out;

    char* ws = (char*)d_ws;
    size_t off = 0;
    auto alloc = [&](size_t bytes) {
        void* p = ws + off;
        off = (off + bytes + 255) & ~(size_t)255;
        return p;
    };
    int* rowbeg = (int*)alloc((size_t)NN * 4);
    int* rowend = (int*)alloc((size_t)NN * 4);
    int* gcur   = (int*)alloc((NB + 1) * 4);
    int* col    = (int*)alloc((size_t)NB * BSLOT * 4);   // gapped CSR
    unsigned short* xb   = (unsigned short*)alloc((size_t)NN * D * 2);
    unsigned short* aggb = (unsigned short*)alloc((size_t)NN * D * 2);
    unsigned short* h1b  = (unsigned short*)alloc((size_t)NN * D * 2);
    unsigned short* wb   = (unsigned short*)alloc((size_t)4 * D * D * 2);
    unsigned short* w1lb = wb;
    unsigned short* w1rb = wb + D * D;
    unsigned short* w2lb = wb + 2 * D * D;
    unsigned short* w2rb = wb + 3 * D * D;
    // ebuf (7.2 MB) aliases h1b (25.6 MB): ebuf dead before h1b is written
    unsigned* ebuf = (unsigned*)h1b;

    // ---- CSR build: self-sizing bucket regions, one sort block per bucket ----
    init_gcur<<<1, 128, 0, stream>>>(gcur);
    bin_scatter<<<(NE + BCHUNK - 1) / BCHUNK, 256, 0, stream>>>(ei, gcur, ebuf);
    sort_bucket<<<NB, 1024, 0, stream>>>(ebuf, gcur, rowbeg, rowend, col);

    // ---- bf16 conversions ----
    conv_f2b<<<(NN * D / 4 + 255) / 256, 256, 0, stream>>>(x, xb, NN * D);
    conv_w4<<<(4 * D * D / 4 + 255) / 256, 256, 0, stream>>>(W1l, W1r, W2l, W2r, wb);

    // ---- layer 1 ----
    aggregate<<<(NN + 3) / 4, 256, 0, stream>>>(xb, rowbeg, rowend, col, aggb);
    sage_gemm_mfma<0><<<(NN + 63) / 64, 256, 0, stream>>>(aggb, xb, w1lb, w1rb, b1,
                                                          nullptr, h1b);
    // ---- layer 2 ----
    aggregate<<<(NN + 3) / 4, 256, 0, stream>>>(h1b, rowbeg, rowend, col, aggb);
    sage_gemm_mfma<1><<<(NN + 63) / 64, 256, 0, stream>>>(aggb, h1b, w2lb, w2rb, b2,
                                                          out, nullptr);
}

// Round 15
// 250.871 us; speedup vs baseline: 1.2775x; 1.0617x over previous
//
#include <hip/hip_runtime.h>
#include <hip/hip_bf16.h>

#define NN 100000
#define NE 1600000
#define D  128
#define NB 196           // dst buckets of 512 nodes (dst>>9)
#define BSLOT 10240      // fixed slots per bucket region (mean 8192 + 22 sigma)
#define BCHUNK 8192      // edges per binning block

typedef short bf16x8 __attribute__((ext_vector_type(8)));
typedef float f32x4 __attribute__((ext_vector_type(4)));

static __device__ inline unsigned short f2b(float f) {
    __hip_bfloat16 b = __float2bfloat16(f);   // RNE
    unsigned short u;
    __builtin_memcpy(&u, &b, 2);
    return u;
}

// bin edges by dst>>9 into packed 4B entries: (dstLocal9<<17) | src17.
// 1024 threads (16 waves/CU — r14 fix: 256thr left this kernel at 4 waves/CU,
// latency-bound). BCHUNK stays 8192 so per-(block,bucket) runs stay ~42
// entries = 168B (shrinking runs would recreate r11 cross-XCD line sharing).
__global__ __launch_bounds__(1024) void bin_scatter(const int* __restrict__ ei,
                                                    int* __restrict__ gcur,
                                                    unsigned* __restrict__ ebuf) {
    __shared__ int hist[NB];
    __shared__ int base_s[NB];
    int chunk0 = blockIdx.x * BCHUNK;
    for (int t = threadIdx.x; t < NB; t += 1024) hist[t] = 0;
    __syncthreads();
    for (int i = 0; i < BCHUNK; i += 1024) {
        int e = chunk0 + i + threadIdx.x;
        if (e < NE) atomicAdd(&hist[ei[NE + e] >> 9], 1);
    }
    __syncthreads();
    for (int t = threadIdx.x; t < NB; t += 1024) {
        base_s[t] = hist[t] ? atomicAdd(&gcur[t], hist[t]) : 0;
        hist[t] = 0;
    }
    __syncthreads();
    for (int i = 0; i < BCHUNK; i += 1024) {
        int e = chunk0 + i + threadIdx.x;
        if (e < NE) {
            int s = ei[e];
            int d = ei[NE + e];
            int b = d >> 9;
            int off = atomicAdd(&hist[b], 1);
            ebuf[(size_t)base_s[b] + off] = ((unsigned)(d & 511) << 17) | (unsigned)s;
        }
    }
}

// One block per 512-node bucket (196 blocks x 512 thr — spread over ~all CUs):
// per-node counts (native LDS int atomics), 512-wide LDS scan ->
// rowbeg/rowend (gapped CSR), scatter col through LDS cursors.
// Bucket's col window owned by ONE block on ONE XCD (r11 lesson).
__global__ __launch_bounds__(512) void sort_bucket(
    const unsigned* __restrict__ ebuf, const int* __restrict__ gcur,
    int* __restrict__ rowbeg, int* __restrict__ rowend, int* __restrict__ col)
{
    __shared__ int cnt[512];
    __shared__ int tmp[512];
    __shared__ int cur[512];
    const int b = blockIdx.x;
    const int t = threadIdx.x;
    const int beg = b * BSLOT;
    const int end = gcur[b];
    const int node0 = b << 9;

    cnt[t] = 0;
    __syncthreads();
    for (int j = beg + t; j < end; j += 512)
        atomicAdd(&cnt[ebuf[j] >> 17], 1);
    __syncthreads();

    int v = cnt[t];
    tmp[t] = v;
    __syncthreads();
    for (int off = 1; off < 512; off <<= 1) {
        int tv = (t >= off) ? tmp[t - off] : 0;
        __syncthreads();
        tmp[t] += tv;
        __syncthreads();
    }
    int gpos = beg + (tmp[t] - v);
    if (node0 + t < NN) { rowbeg[node0 + t] = gpos; rowend[node0 + t] = gpos + v; }
    cur[t] = gpos;
    __syncthreads();

    for (int j = beg + t; j < end; j += 512) {
        unsigned p = ebuf[j];
        int pos = atomicAdd(&cur[p >> 17], 1);
        col[pos] = (int)(p & 0x1ffffu);
    }
}

// fp32 -> bf16 conversion, 4 elems/thread
__global__ void conv_f2b(const float* __restrict__ src,
                         unsigned short* __restrict__ dst, int n) {
    int i = (blockIdx.x * 256 + threadIdx.x) * 4;
    if (i + 3 < n) {
        float4 v = *(const float4*)(src + i);
        ushort4 o;
        o.x = f2b(v.x); o.y = f2b(v.y); o.z = f2b(v.z); o.w = f2b(v.w);
        *(ushort4*)(dst + i) = o;
    } else {
        for (; i < n; ++i) dst[i] = f2b(src[i]);
    }
}

// all 4 weight matrices in one launch; block 0 also inits the bucket cursors
// (folded init_gcur: this kernel is ordered before bin_scatter on the stream)
__global__ void conv_w4(const float* __restrict__ s0, const float* __restrict__ s1,
                        const float* __restrict__ s2, const float* __restrict__ s3,
                        unsigned short* __restrict__ dst, int* __restrict__ gcur) {
    if (blockIdx.x == 0 && threadIdx.x < NB) gcur[threadIdx.x] = threadIdx.x * BSLOT;
    int i = (blockIdx.x * 256 + threadIdx.x) * 4;   // [0, 4*D*D)
    const float* srcs[4] = {s0, s1, s2, s3};
    const float* s = srcs[i >> 14];                 // D*D = 16384
    float4 v = *(const float4*)(s + (i & 16383));
    ushort4 o;
    o.x = f2b(v.x); o.y = f2b(v.y); o.z = f2b(v.z); o.w = f2b(v.w);
    *(ushort4*)(dst + i) = o;
}

// mean aggregation over bf16 features; two 32-lane halves per wave, uint2/lane
// (round-8 proven gather: 62 us, FETCH at the per-XCD coverage floor;
// standalone on purpose — r13 showed fusing with the GEMM costs 35%)
__global__ __launch_bounds__(256) void aggregate(const unsigned short* __restrict__ hb,
                                                 const int* __restrict__ rowbeg,
                                                 const int* __restrict__ rowend,
                                                 const int* __restrict__ col,
                                                 unsigned short* __restrict__ aggb) {
    int node = blockIdx.x * 4 + (threadIdx.x >> 6);
    if (node >= NN) return;
    int lane = threadIdx.x & 63;
    int half = lane >> 5;
    int sl   = lane & 31;
    int beg = rowbeg[node], end = rowend[node];
    const uint2* hp = (const uint2*)hb;   // 32 uint2 per row
    float a0 = 0.f, a1 = 0.f, a2 = 0.f, a3 = 0.f;

    int j = beg + half;
    for (; j + 6 < end; j += 8) {
        int c0 = col[j];
        int c1 = col[j + 2];
        int c2 = col[j + 4];
        int c3 = col[j + 6];
        uint2 v0 = hp[c0 * 32 + sl];
        uint2 v1 = hp[c1 * 32 + sl];
        uint2 v2 = hp[c2 * 32 + sl];
        uint2 v3 = hp[c3 * 32 + sl];
        a0 += __uint_as_float(v0.x << 16) + __uint_as_float(v1.x << 16)
            + __uint_as_float(v2.x << 16) + __uint_as_float(v3.x << 16);
        a1 += __uint_as_float(v0.x & 0xffff0000u) + __uint_as_float(v1.x & 0xffff0000u)
            + __uint_as_float(v2.x & 0xffff0000u) + __uint_as_float(v3.x & 0xffff0000u);
        a2 += __uint_as_float(v0.y << 16) + __uint_as_float(v1.y << 16)
            + __uint_as_float(v2.y << 16) + __uint_as_float(v3.y << 16);
        a3 += __uint_as_float(v0.y & 0xffff0000u) + __uint_as_float(v1.y & 0xffff0000u)
            + __uint_as_float(v2.y & 0xffff0000u) + __uint_as_float(v3.y & 0xffff0000u);
    }
    for (; j < end; j += 2) {
        uint2 v = hp[col[j] * 32 + sl];
        a0 += __uint_as_float(v.x << 16);
        a1 += __uint_as_float(v.x & 0xffff0000u);
        a2 += __uint_as_float(v.y << 16);
        a3 += __uint_as_float(v.y & 0xffff0000u);
    }

    a0 += __shfl_xor(a0, 32);
    a1 += __shfl_xor(a1, 32);
    a2 += __shfl_xor(a2, 32);
    a3 += __shfl_xor(a3, 32);

    int deg = end - beg;
    float inv = 1.0f / (float)(deg > 1 ? deg : 1);
    if (half == 0) {
        uint2 o;
        o.x = (unsigned)f2b(a0 * inv) | ((unsigned)f2b(a1 * inv) << 16);
        o.y = (unsigned)f2b(a2 * inv) | ((unsigned)f2b(a3 * inv) << 16);
        ((uint2*)aggb)[(size_t)node * 32 + sl] = o;
    }
}

// out[n][j] = leaky_relu( sum_k agg[n][k]*Wl[j][k] + h[n][k]*Wr[j][k] + b[j], 0.5 )
// MFMA 16x16x32 bf16. Block = 256 thr = 4 waves (2x2), tile 64 rows x 128 cols.
// A/H slabs staged via coalesced uint4 loads into 272B-padded LDS rows.
template <int OUT_F32>
__global__ __launch_bounds__(256) void sage_gemm_mfma(
    const unsigned short* __restrict__ Ab,   // [NN][128] aggregated
    const unsigned short* __restrict__ Hb,   // [NN][128] root
    const unsigned short* __restrict__ Wlb,  // [128][128], row j contiguous in k
    const unsigned short* __restrict__ Wrb,
    const float* __restrict__ bias,
    float* __restrict__ outf,
    unsigned short* __restrict__ outb)
{
    __shared__ unsigned short sA[64][136];   // 17.4 KB (272B rows)
    __shared__ unsigned short sH[64][136];
    const int tid = threadIdx.x;
    const int block0 = blockIdx.x * 64;

    {
        int i = tid;   // 64 rows x 16 quads = 1024; 4 iters of 256 threads
#pragma unroll
        for (int k = 0; k < 4; ++k, i += 256) {
            int row = i >> 4, c16 = i & 15;
            int grow = block0 + row; if (grow >= NN) grow = NN - 1;
            *(uint4*)(&sA[row][c16 * 8]) = *(const uint4*)(Ab + (size_t)grow * D + c16 * 8);
            *(uint4*)(&sH[row][c16 * 8]) = *(const uint4*)(Hb + (size_t)grow * D + c16 * 8);
        }
    }
    __syncthreads();

    const int lane = tid & 63;
    const int wid  = tid >> 6;
    const int r  = lane & 15;
    const int kg = lane >> 4;
    const int rbase = (wid >> 1) * 32;     // 0 or 32
    const int col0  = (wid & 1) * 64;

    float bv[4];
#pragma unroll
    for (int c = 0; c < 4; ++c) bv[c] = bias[col0 + c * 16 + r];

    f32x4 acc[2][4];
#pragma unroll
    for (int m = 0; m < 2; ++m)
#pragma unroll
        for (int c = 0; c < 4; ++c) acc[m][c] = (f32x4){0.f, 0.f, 0.f, 0.f};

#pragma unroll
    for (int ks = 0; ks < 8; ++ks) {
        const unsigned short (*S)[136] = (ks < 4) ? sA : sH;
        const unsigned short* W = (ks < 4) ? Wlb : Wrb;
        const int kk = (ks & 3) * 32 + kg * 8;
        bf16x8 a0 = *(const bf16x8*)(&S[rbase + r][kk]);
        bf16x8 a1 = *(const bf16x8*)(&S[rbase + 16 + r][kk]);
        bf16x8 bw[4];
#pragma unroll
        for (int c = 0; c < 4; ++c)
            bw[c] = *(const bf16x8*)(W + (size_t)(col0 + c * 16 + r) * D + kk);
#pragma unroll
        for (int c = 0; c < 4; ++c) {
            acc[0][c] = __builtin_amdgcn_mfma_f32_16x16x32_bf16(a0, bw[c], acc[0][c], 0, 0, 0);
            acc[1][c] = __builtin_amdgcn_mfma_f32_16x16x32_bf16(a1, bw[c], acc[1][c], 0, 0, 0);
        }
    }

    // C/D layout: col = c*16 + (lane&15), row = m*16 + (lane>>4)*4 + q   [m89]
#pragma unroll
    for (int m = 0; m < 2; ++m) {
#pragma unroll
        for (int q = 0; q < 4; ++q) {
            int row = block0 + rbase + m * 16 + kg * 4 + q;
            if (row < NN) {
#pragma unroll
                for (int c = 0; c < 4; ++c) {
                    float v = acc[m][c][q] + bv[c];
                    v = v > 0.f ? v : 0.5f * v;
                    int colj = col0 + c * 16 + r;
                    if (OUT_F32) outf[(size_t)row * D + colj] = v;
                    else         outb[(size_t)row * D + colj] = f2b(v);
                }
            }
        }
    }
}

extern "C" void kernel_launch(void* const* d_in, const int* in_sizes, int n_in,
                              void* d_out, int out_size, void* d_ws, size_t ws_size,
                              hipStream_t stream) {
    const float* x   = (const float*)d_in[0];
    const int*   ei  = (const int*)d_in[1];
    const float* W1l = (const float*)d_in[2];
    const float* W1r = (const float*)d_in[3];
    const float* b1  = (const float*)d_in[4];
    const float* W2l = (const float*)d_in[5];
    const float* W2r = (const float*)d_in[6];
    const float* b2  = (const float*)d_in[7];
    float* out = (float*)d_out;

    char* ws = (char*)d_ws;
    size_t off = 0;
    auto alloc = [&](size_t bytes) {
        void* p = ws + off;
        off = (off + bytes + 255) & ~(size_t)255;
        return p;
    };
    int* rowbeg = (int*)alloc((size_t)NN * 4);
    int* rowend = (int*)alloc((size_t)NN * 4);
    int* gcur   = (int*)alloc((NB + 1) * 4);
    int* col    = (int*)alloc((size_t)NB * BSLOT * 4);   // gapped CSR (8 MB)
    unsigned short* xb   = (unsigned short*)alloc((size_t)NN * D * 2);
    unsigned short* aggb = (unsigned short*)alloc((size_t)NN * D * 2);
    unsigned short* h1b  = (unsigned short*)alloc((size_t)NN * D * 2);
    unsigned short* wb   = (unsigned short*)alloc((size_t)4 * D * D * 2);
    unsigned short* w1lb = wb;
    unsigned short* w1rb = wb + D * D;
    unsigned short* w2lb = wb + 2 * D * D;
    unsigned short* w2rb = wb + 3 * D * D;
    // ebuf (8 MB) aliases h1b (25.6 MB): ebuf dead before h1b is written
    unsigned* ebuf = (unsigned*)h1b;

    // ---- conversions first (conv_w4 block 0 inits gcur before bin_scatter) ----
    conv_f2b<<<(NN * D / 4 + 255) / 256, 256, 0, stream>>>(x, xb, NN * D);
    conv_w4<<<(4 * D * D / 4 + 255) / 256, 256, 0, stream>>>(W1l, W1r, W2l, W2r, wb, gcur);

    // ---- CSR build: self-sizing bucket regions, one sort block per bucket ----
    bin_scatter<<<(NE + BCHUNK - 1) / BCHUNK, 1024, 0, stream>>>(ei, gcur, ebuf);
    sort_bucket<<<NB, 512, 0, stream>>>(ebuf, gcur, rowbeg, rowend, col);

    // ---- layer 1 ----
    aggregate<<<(NN + 3) / 4, 256, 0, stream>>>(xb, rowbeg, rowend, col, aggb);
    sage_gemm_mfma<0><<<(NN + 63) / 64, 256, 0, stream>>>(aggb, xb, w1lb, w1rb, b1,
                                                          nullptr, h1b);
    // ---- layer 2 ----
    aggregate<<<(NN + 3) / 4, 256, 0, stream>>>(h1b, rowbeg, rowend, col, aggb);
    sage_gemm_mfma<1><<<(NN + 63) / 64, 256, 0, stream>>>(aggb, h1b, w2lb, w2rb, b2,
                                                          out, nullptr);
}

// Round 16
// 244.820 us; speedup vs baseline: 1.3091x; 1.0247x over previous
//
#include <hip/hip_runtime.h>
#include <hip/hip_bf16.h>

#define NN 100000
#define NE 1600000
#define D  128
#define NB 196           // dst buckets of 512 nodes (dst>>9)
#define BSLOT 10240      // fixed slots per bucket region (mean 8192 + 22 sigma)
#define BCHUNK 8192      // edges per binning block

typedef short bf16x8 __attribute__((ext_vector_type(8)));
typedef float f32x4 __attribute__((ext_vector_type(4)));

static __device__ inline unsigned short f2b(float f) {
    __hip_bfloat16 b = __float2bfloat16(f);   // RNE
    unsigned short u;
    __builtin_memcpy(&u, &b, 2);
    return u;
}

// bin edges by dst>>9 into packed 4B entries: (dstLocal9<<17) | src17.
// 1024 threads (16 waves/CU). BCHUNK 8192 keeps per-(block,bucket) runs ~42
// entries = 168B (shrinking runs would recreate r11 cross-XCD line sharing).
__global__ __launch_bounds__(1024) void bin_scatter(const int* __restrict__ ei,
                                                    int* __restrict__ gcur,
                                                    unsigned* __restrict__ ebuf) {
    __shared__ int hist[NB];
    __shared__ int base_s[NB];
    int chunk0 = blockIdx.x * BCHUNK;
    for (int t = threadIdx.x; t < NB; t += 1024) hist[t] = 0;
    __syncthreads();
    for (int i = 0; i < BCHUNK; i += 1024) {
        int e = chunk0 + i + threadIdx.x;
        if (e < NE) atomicAdd(&hist[ei[NE + e] >> 9], 1);
    }
    __syncthreads();
    for (int t = threadIdx.x; t < NB; t += 1024) {
        base_s[t] = hist[t] ? atomicAdd(&gcur[t], hist[t]) : 0;
        hist[t] = 0;
    }
    __syncthreads();
    for (int i = 0; i < BCHUNK; i += 1024) {
        int e = chunk0 + i + threadIdx.x;
        if (e < NE) {
            int s = ei[e];
            int d = ei[NE + e];
            int b = d >> 9;
            int off = atomicAdd(&hist[b], 1);
            ebuf[(size_t)base_s[b] + off] = ((unsigned)(d & 511) << 17) | (unsigned)s;
        }
    }
}

// One block per 512-node bucket: per-node counts (native LDS int atomics),
// 512-wide LDS scan -> rowbeg/rowend (gapped CSR), scatter col through LDS
// cursors. Bucket's col window owned by ONE block on ONE XCD (r11 lesson).
__global__ __launch_bounds__(512) void sort_bucket(
    const unsigned* __restrict__ ebuf, const int* __restrict__ gcur,
    int* __restrict__ rowbeg, int* __restrict__ rowend, int* __restrict__ col)
{
    __shared__ int cnt[512];
    __shared__ int tmp[512];
    __shared__ int cur[512];
    const int b = blockIdx.x;
    const int t = threadIdx.x;
    const int beg = b * BSLOT;
    const int end = gcur[b];
    const int node0 = b << 9;

    cnt[t] = 0;
    __syncthreads();
    for (int j = beg + t; j < end; j += 512)
        atomicAdd(&cnt[ebuf[j] >> 17], 1);
    __syncthreads();

    int v = cnt[t];
    tmp[t] = v;
    __syncthreads();
    for (int off = 1; off < 512; off <<= 1) {
        int tv = (t >= off) ? tmp[t - off] : 0;
        __syncthreads();
        tmp[t] += tv;
        __syncthreads();
    }
    int gpos = beg + (tmp[t] - v);
    if (node0 + t < NN) { rowbeg[node0 + t] = gpos; rowend[node0 + t] = gpos + v; }
    cur[t] = gpos;
    __syncthreads();

    for (int j = beg + t; j < end; j += 512) {
        unsigned p = ebuf[j];
        int pos = atomicAdd(&cur[p >> 17], 1);
        col[pos] = (int)(p & 0x1ffffu);
    }
}

// fp32 -> bf16 conversion, 4 elems/thread
__global__ void conv_f2b(const float* __restrict__ src,
                         unsigned short* __restrict__ dst, int n) {
    int i = (blockIdx.x * 256 + threadIdx.x) * 4;
    if (i + 3 < n) {
        float4 v = *(const float4*)(src + i);
        ushort4 o;
        o.x = f2b(v.x); o.y = f2b(v.y); o.z = f2b(v.z); o.w = f2b(v.w);
        *(ushort4*)(dst + i) = o;
    } else {
        for (; i < n; ++i) dst[i] = f2b(src[i]);
    }
}

// all 4 weight matrices in one launch; block 0 also inits the bucket cursors
__global__ void conv_w4(const float* __restrict__ s0, const float* __restrict__ s1,
                        const float* __restrict__ s2, const float* __restrict__ s3,
                        unsigned short* __restrict__ dst, int* __restrict__ gcur) {
    if (blockIdx.x == 0 && threadIdx.x < NB) gcur[threadIdx.x] = threadIdx.x * BSLOT;
    int i = (blockIdx.x * 256 + threadIdx.x) * 4;   // [0, 4*D*D)
    const float* srcs[4] = {s0, s1, s2, s3};
    const float* s = srcs[i >> 14];                 // D*D = 16384
    float4 v = *(const float4*)(s + (i & 16383));
    ushort4 o;
    o.x = f2b(v.x); o.y = f2b(v.y); o.z = f2b(v.z); o.w = f2b(v.w);
    *(ushort4*)(dst + i) = o;
}

// mean aggregation over bf16 features — uint4/lane variant.
// Wave = 4 groups of 16 lanes; each group owns one edge slot (every 4th edge),
// lane loads uint4 (16B): one load instruction covers 4 edges (vs 2 with the
// r8 uint2 shape) -> half the load-issue and address VALU per byte. 4-deep
// unroll = 16 edges in flight/wave. Group merge: shfl_xor(16,32) tree.
// Traffic is byte-identical to r8 (FETCH stays at the coverage floor).
__global__ __launch_bounds__(256) void aggregate(const unsigned short* __restrict__ hb,
                                                 const int* __restrict__ rowbeg,
                                                 const int* __restrict__ rowend,
                                                 const int* __restrict__ col,
                                                 unsigned short* __restrict__ aggb) {
    int node = blockIdx.x * 4 + (threadIdx.x >> 6);
    if (node >= NN) return;
    int lane = threadIdx.x & 63;
    int grp = lane >> 4;     // edge slot 0..3
    int gl  = lane & 15;     // uint4 index within the 256B row
    int beg = rowbeg[node], end = rowend[node];
    const uint4* hp = (const uint4*)hb;   // 16 uint4 per row
    float a0 = 0.f, a1 = 0.f, a2 = 0.f, a3 = 0.f;
    float a4 = 0.f, a5 = 0.f, a6 = 0.f, a7 = 0.f;

#define ACC8(V)                                                     \
    {                                                               \
        a0 += __uint_as_float((V).x << 16);                         \
        a1 += __uint_as_float((V).x & 0xffff0000u);                 \
        a2 += __uint_as_float((V).y << 16);                         \
        a3 += __uint_as_float((V).y & 0xffff0000u);                 \
        a4 += __uint_as_float((V).z << 16);                         \
        a5 += __uint_as_float((V).z & 0xffff0000u);                 \
        a6 += __uint_as_float((V).w << 16);                         \
        a7 += __uint_as_float((V).w & 0xffff0000u);                 \
    }

    int j = beg + grp;
    for (; j + 12 < end; j += 16) {       // 16 edges in flight per wave
        int c0 = col[j];
        int c1 = col[j + 4];
        int c2 = col[j + 8];
        int c3 = col[j + 12];
        uint4 v0 = hp[(size_t)c0 * 16 + gl];
        uint4 v1 = hp[(size_t)c1 * 16 + gl];
        uint4 v2 = hp[(size_t)c2 * 16 + gl];
        uint4 v3 = hp[(size_t)c3 * 16 + gl];
        ACC8(v0); ACC8(v1); ACC8(v2); ACC8(v3);
    }
    for (; j < end; j += 4) {
        uint4 v = hp[(size_t)col[j] * 16 + gl];
        ACC8(v);
    }
#undef ACC8

    // merge the 4 groups (each lane's channels align with lane^16, lane^32)
#pragma unroll
    for (int off = 16; off < 64; off <<= 1) {
        a0 += __shfl_xor(a0, off);
        a1 += __shfl_xor(a1, off);
        a2 += __shfl_xor(a2, off);
        a3 += __shfl_xor(a3, off);
        a4 += __shfl_xor(a4, off);
        a5 += __shfl_xor(a5, off);
        a6 += __shfl_xor(a6, off);
        a7 += __shfl_xor(a7, off);
    }

    int deg = end - beg;
    float inv = 1.0f / (float)(deg > 1 ? deg : 1);
    if (grp == 0) {
        uint4 o;
        o.x = (unsigned)f2b(a0 * inv) | ((unsigned)f2b(a1 * inv) << 16);
        o.y = (unsigned)f2b(a2 * inv) | ((unsigned)f2b(a3 * inv) << 16);
        o.z = (unsigned)f2b(a4 * inv) | ((unsigned)f2b(a5 * inv) << 16);
        o.w = (unsigned)f2b(a6 * inv) | ((unsigned)f2b(a7 * inv) << 16);
        ((uint4*)aggb)[(size_t)node * 16 + gl] = o;
    }
}

// out[n][j] = leaky_relu( sum_k agg[n][k]*Wl[j][k] + h[n][k]*Wr[j][k] + b[j], 0.5 )
// MFMA 16x16x32 bf16. Block = 256 thr = 4 waves (2x2), tile 64 rows x 128 cols.
// A/H slabs staged via coalesced uint4 loads into 272B-padded LDS rows.
template <int OUT_F32>
__global__ __launch_bounds__(256) void sage_gemm_mfma(
    const unsigned short* __restrict__ Ab,   // [NN][128] aggregated
    const unsigned short* __restrict__ Hb,   // [NN][128] root
    const unsigned short* __restrict__ Wlb,  // [128][128], row j contiguous in k
    const unsigned short* __restrict__ Wrb,
    const float* __restrict__ bias,
    float* __restrict__ outf,
    unsigned short* __restrict__ outb)
{
    __shared__ unsigned short sA[64][136];   // 17.4 KB (272B rows)
    __shared__ unsigned short sH[64][136];
    const int tid = threadIdx.x;
    const int block0 = blockIdx.x * 64;

    {
        int i = tid;   // 64 rows x 16 quads = 1024; 4 iters of 256 threads
#pragma unroll
        for (int k = 0; k < 4; ++k, i += 256) {
            int row = i >> 4, c16 = i & 15;
            int grow = block0 + row; if (grow >= NN) grow = NN - 1;
            *(uint4*)(&sA[row][c16 * 8]) = *(const uint4*)(Ab + (size_t)grow * D + c16 * 8);
            *(uint4*)(&sH[row][c16 * 8]) = *(const uint4*)(Hb + (size_t)grow * D + c16 * 8);
        }
    }
    __syncthreads();

    const int lane = tid & 63;
    const int wid  = tid >> 6;
    const int r  = lane & 15;
    const int kg = lane >> 4;
    const int rbase = (wid >> 1) * 32;     // 0 or 32
    const int col0  = (wid & 1) * 64;

    float bv[4];
#pragma unroll
    for (int c = 0; c < 4; ++c) bv[c] = bias[col0 + c * 16 + r];

    f32x4 acc[2][4];
#pragma unroll
    for (int m = 0; m < 2; ++m)
#pragma unroll
        for (int c = 0; c < 4; ++c) acc[m][c] = (f32x4){0.f, 0.f, 0.f, 0.f};

#pragma unroll
    for (int ks = 0; ks < 8; ++ks) {
        const unsigned short (*S)[136] = (ks < 4) ? sA : sH;
        const unsigned short* W = (ks < 4) ? Wlb : Wrb;
        const int kk = (ks & 3) * 32 + kg * 8;
        bf16x8 a0 = *(const bf16x8*)(&S[rbase + r][kk]);
        bf16x8 a1 = *(const bf16x8*)(&S[rbase + 16 + r][kk]);
        bf16x8 bw[4];
#pragma unroll
        for (int c = 0; c < 4; ++c)
            bw[c] = *(const bf16x8*)(W + (size_t)(col0 + c * 16 + r) * D + kk);
#pragma unroll
        for (int c = 0; c < 4; ++c) {
            acc[0][c] = __builtin_amdgcn_mfma_f32_16x16x32_bf16(a0, bw[c], acc[0][c], 0, 0, 0);
            acc[1][c] = __builtin_amdgcn_mfma_f32_16x16x32_bf16(a1, bw[c], acc[1][c], 0, 0, 0);
        }
    }

    // C/D layout: col = c*16 + (lane&15), row = m*16 + (lane>>4)*4 + q   [m89]
#pragma unroll
    for (int m = 0; m < 2; ++m) {
#pragma unroll
        for (int q = 0; q < 4; ++q) {
            int row = block0 + rbase + m * 16 + kg * 4 + q;
            if (row < NN) {
#pragma unroll
                for (int c = 0; c < 4; ++c) {
                    float v = acc[m][c][q] + bv[c];
                    v = v > 0.f ? v : 0.5f * v;
                    int colj = col0 + c * 16 + r;
                    if (OUT_F32) outf[(size_t)row * D + colj] = v;
                    else         outb[(size_t)row * D + colj] = f2b(v);
                }
            }
        }
    }
}

extern "C" void kernel_launch(void* const* d_in, const int* in_sizes, int n_in,
                              void* d_out, int out_size, void* d_ws, size_t ws_size,
                              hipStream_t stream) {
    const float* x   = (const float*)d_in[0];
    const int*   ei  = (const int*)d_in[1];
    const float* W1l = (const float*)d_in[2];
    const float* W1r = (const float*)d_in[3];
    const float* b1  = (const float*)d_in[4];
    const float* W2l = (const float*)d_in[5];
    const float* W2r = (const float*)d_in[6];
    const float* b2  = (const float*)d_in[7];
    float* out = (float*)d_out;

    char* ws = (char*)d_ws;
    size_t off = 0;
    auto alloc = [&](size_t bytes) {
        void* p = ws + off;
        off = (off + bytes + 255) & ~(size_t)255;
        return p;
    };
    int* rowbeg = (int*)alloc((size_t)NN * 4);
    int* rowend = (int*)alloc((size_t)NN * 4);
    int* gcur   = (int*)alloc((NB + 1) * 4);
    int* col    = (int*)alloc((size_t)NB * BSLOT * 4);   // gapped CSR (8 MB)
    unsigned short* xb   = (unsigned short*)alloc((size_t)NN * D * 2);
    unsigned short* aggb = (unsigned short*)alloc((size_t)NN * D * 2);
    unsigned short* h1b  = (unsigned short*)alloc((size_t)NN * D * 2);
    unsigned short* wb   = (unsigned short*)alloc((size_t)4 * D * D * 2);
    unsigned short* w1lb = wb;
    unsigned short* w1rb = wb + D * D;
    unsigned short* w2lb = wb + 2 * D * D;
    unsigned short* w2rb = wb + 3 * D * D;
    // ebuf (8 MB) aliases h1b (25.6 MB): ebuf dead before h1b is written
    unsigned* ebuf = (unsigned*)h1b;

    // ---- conversions first (conv_w4 block 0 inits gcur before bin_scatter) ----
    conv_f2b<<<(NN * D / 4 + 255) / 256, 256, 0, stream>>>(x, xb, NN * D);
    conv_w4<<<(4 * D * D / 4 + 255) / 256, 256, 0, stream>>>(W1l, W1r, W2l, W2r, wb, gcur);

    // ---- CSR build: self-sizing bucket regions, one sort block per bucket ----
    bin_scatter<<<(NE + BCHUNK - 1) / BCHUNK, 1024, 0, stream>>>(ei, gcur, ebuf);
    sort_bucket<<<NB, 512, 0, stream>>>(ebuf, gcur, rowbeg, rowend, col);

    // ---- layer 1 ----
    aggregate<<<(NN + 3) / 4, 256, 0, stream>>>(xb, rowbeg, rowend, col, aggb);
    sage_gemm_mfma<0><<<(NN + 63) / 64, 256, 0, stream>>>(aggb, xb, w1lb, w1rb, b1,
                                                          nullptr, h1b);
    // ---- layer 2 ----
    aggregate<<<(NN + 3) / 4, 256, 0, stream>>>(h1b, rowbeg, rowend, col, aggb);
    sage_gemm_mfma<1><<<(NN + 63) / 64, 256, 0, stream>>>(aggb, h1b, w2lb, w2rb, b2,
                                                          out, nullptr);
}

// Round 17
// 212.912 us; speedup vs baseline: 1.5053x; 1.1499x over previous
//
#include <hip/hip_runtime.h>
#include <hip/hip_bf16.h>

#define NN 100000
#define NE 1600000
#define D  128
#define NB 196           // dst buckets of 512 nodes (dst>>9)
#define BSLOT 10240      // fixed slots per bucket region (mean 8192 + 22 sigma)
#define BCHUNK 8192      // edges per binning block

typedef short bf16x8 __attribute__((ext_vector_type(8)));
typedef float f32x4 __attribute__((ext_vector_type(4)));

static __device__ inline unsigned short f2b(float f) {
    __hip_bfloat16 b = __float2bfloat16(f);   // RNE
    unsigned short u;
    __builtin_memcpy(&u, &b, 2);
    return u;
}

// bin edges by dst>>9 into packed 4B entries: (dstLocal9<<17) | src17.
// 1024 threads (16 waves/CU). BCHUNK 8192 keeps per-(block,bucket) runs ~42
// entries = 168B (shrinking runs would recreate r11 cross-XCD line sharing).
__global__ __launch_bounds__(1024) void bin_scatter(const int* __restrict__ ei,
                                                    int* __restrict__ gcur,
                                                    unsigned* __restrict__ ebuf) {
    __shared__ int hist[NB];
    __shared__ int base_s[NB];
    int chunk0 = blockIdx.x * BCHUNK;
    for (int t = threadIdx.x; t < NB; t += 1024) hist[t] = 0;
    __syncthreads();
    for (int i = 0; i < BCHUNK; i += 1024) {
        int e = chunk0 + i + threadIdx.x;
        if (e < NE) atomicAdd(&hist[ei[NE + e] >> 9], 1);
    }
    __syncthreads();
    for (int t = threadIdx.x; t < NB; t += 1024) {
        base_s[t] = hist[t] ? atomicAdd(&gcur[t], hist[t]) : 0;
        hist[t] = 0;
    }
    __syncthreads();
    for (int i = 0; i < BCHUNK; i += 1024) {
        int e = chunk0 + i + threadIdx.x;
        if (e < NE) {
            int s = ei[e];
            int d = ei[NE + e];
            int b = d >> 9;
            int off = atomicAdd(&hist[b], 1);
            ebuf[(size_t)base_s[b] + off] = ((unsigned)(d & 511) << 17) | (unsigned)s;
        }
    }
}

// One block per 512-node bucket: per-node counts (native LDS int atomics),
// 512-wide LDS scan -> rowbeg/rowend (gapped CSR), scatter col through LDS
// cursors. Bucket's col window owned by ONE block on ONE XCD (r11 lesson).
__global__ __launch_bounds__(512) void sort_bucket(
    const unsigned* __restrict__ ebuf, const int* __restrict__ gcur,
    int* __restrict__ rowbeg, int* __restrict__ rowend, int* __restrict__ col)
{
    __shared__ int cnt[512];
    __shared__ int tmp[512];
    __shared__ int cur[512];
    const int b = blockIdx.x;
    const int t = threadIdx.x;
    const int beg = b * BSLOT;
    const int end = gcur[b];
    const int node0 = b << 9;

    cnt[t] = 0;
    __syncthreads();
    for (int j = beg + t; j < end; j += 512)
        atomicAdd(&cnt[ebuf[j] >> 17], 1);
    __syncthreads();

    int v = cnt[t];
    tmp[t] = v;
    __syncthreads();
    for (int off = 1; off < 512; off <<= 1) {
        int tv = (t >= off) ? tmp[t - off] : 0;
        __syncthreads();
        tmp[t] += tv;
        __syncthreads();
    }
    int gpos = beg + (tmp[t] - v);
    if (node0 + t < NN) { rowbeg[node0 + t] = gpos; rowend[node0 + t] = gpos + v; }
    cur[t] = gpos;
    __syncthreads();

    for (int j = beg + t; j < end; j += 512) {
        unsigned p = ebuf[j];
        int pos = atomicAdd(&cur[p >> 17], 1);
        col[pos] = (int)(p & 0x1ffffu);
    }
}

// One conversion kernel: x -> bf16 (first xn4 threads), then the 4 weight
// matrices with MFMA-fragment swizzle Wt[jb][kb][r][8] (jb=j>>4, kb=k>>3):
// a B-fragment load becomes 16 lanes x contiguous 16B = one 256B chunk
// (4 cache lines/instr vs 16 with row-major W). Block 0 inits gcur.
__global__ void conv_all(const float* __restrict__ x,
                         const float* __restrict__ s0, const float* __restrict__ s1,
                         const float* __restrict__ s2, const float* __restrict__ s3,
                         unsigned short* __restrict__ xb,
                         unsigned short* __restrict__ wb,
                         int* __restrict__ gcur) {
    if (blockIdx.x == 0 && threadIdx.x < NB) gcur[threadIdx.x] = threadIdx.x * BSLOT;
    const int xn4 = NN * D / 4;                     // 3.2M
    int idx = blockIdx.x * 256 + threadIdx.x;
    if (idx < xn4) {
        int i = idx * 4;
        float4 v = *(const float4*)(x + i);
        ushort4 o;
        o.x = f2b(v.x); o.y = f2b(v.y); o.z = f2b(v.z); o.w = f2b(v.w);
        *(ushort4*)(xb + i) = o;
    } else if (idx < xn4 + 4 * D * D / 4) {
        int i = (idx - xn4) * 4;                    // [0, 4*D*D)
        const float* srcs[4] = {s0, s1, s2, s3};
        int m = i >> 14;                            // which matrix
        int rem = i & 16383;
        int j = rem >> 7, k = rem & 127;            // row, col (k%8 in {0,4})
        float4 v = *(const float4*)(srcs[m] + rem);
        ushort4 o;
        o.x = f2b(v.x); o.y = f2b(v.y); o.z = f2b(v.z); o.w = f2b(v.w);
        unsigned short* dst = wb + m * D * D
            + (((j >> 4) * 16 + (k >> 3)) * 16 + (j & 15)) * 8 + (k & 7);
        *(ushort4*)dst = o;
    }
}

// mean aggregation over bf16 features — uint4/lane (r16: 59 us, 3.55 TB/s,
// at the L2-fill-path ceiling; structural). 4 groups of 16 lanes, 16 edges
// in flight/wave, shfl_xor(16,32) merge.
__global__ __launch_bounds__(256) void aggregate(const unsigned short* __restrict__ hb,
                                                 const int* __restrict__ rowbeg,
                                                 const int* __restrict__ rowend,
                                                 const int* __restrict__ col,
                                                 unsigned short* __restrict__ aggb) {
    int node = blockIdx.x * 4 + (threadIdx.x >> 6);
    if (node >= NN) return;
    int lane = threadIdx.x & 63;
    int grp = lane >> 4;     // edge slot 0..3
    int gl  = lane & 15;     // uint4 index within the 256B row
    int beg = rowbeg[node], end = rowend[node];
    const uint4* hp = (const uint4*)hb;   // 16 uint4 per row
    float a0 = 0.f, a1 = 0.f, a2 = 0.f, a3 = 0.f;
    float a4 = 0.f, a5 = 0.f, a6 = 0.f, a7 = 0.f;

#define ACC8(V)                                                     \
    {                                                               \
        a0 += __uint_as_float((V).x << 16);                         \
        a1 += __uint_as_float((V).x & 0xffff0000u);                 \
        a2 += __uint_as_float((V).y << 16);                         \
        a3 += __uint_as_float((V).y & 0xffff0000u);                 \
        a4 += __uint_as_float((V).z << 16);                         \
        a5 += __uint_as_float((V).z & 0xffff0000u);                 \
        a6 += __uint_as_float((V).w << 16);                         \
        a7 += __uint_as_float((V).w & 0xffff0000u);                 \
    }

    int j = beg + grp;
    for (; j + 12 < end; j += 16) {       // 16 edges in flight per wave
        int c0 = col[j];
        int c1 = col[j + 4];
        int c2 = col[j + 8];
        int c3 = col[j + 12];
        uint4 v0 = hp[(size_t)c0 * 16 + gl];
        uint4 v1 = hp[(size_t)c1 * 16 + gl];
        uint4 v2 = hp[(size_t)c2 * 16 + gl];
        uint4 v3 = hp[(size_t)c3 * 16 + gl];
        ACC8(v0); ACC8(v1); ACC8(v2); ACC8(v3);
    }
    for (; j < end; j += 4) {
        uint4 v = hp[(size_t)col[j] * 16 + gl];
        ACC8(v);
    }
#undef ACC8

#pragma unroll
    for (int off = 16; off < 64; off <<= 1) {
        a0 += __shfl_xor(a0, off);
        a1 += __shfl_xor(a1, off);
        a2 += __shfl_xor(a2, off);
        a3 += __shfl_xor(a3, off);
        a4 += __shfl_xor(a4, off);
        a5 += __shfl_xor(a5, off);
        a6 += __shfl_xor(a6, off);
        a7 += __shfl_xor(a7, off);
    }

    int deg = end - beg;
    float inv = 1.0f / (float)(deg > 1 ? deg : 1);
    if (grp == 0) {
        uint4 o;
        o.x = (unsigned)f2b(a0 * inv) | ((unsigned)f2b(a1 * inv) << 16);
        o.y = (unsigned)f2b(a2 * inv) | ((unsigned)f2b(a3 * inv) << 16);
        o.z = (unsigned)f2b(a4 * inv) | ((unsigned)f2b(a5 * inv) << 16);
        o.w = (unsigned)f2b(a6 * inv) | ((unsigned)f2b(a7 * inv) << 16);
        ((uint4*)aggb)[(size_t)node * 16 + gl] = o;
    }
}

// out[n][j] = leaky_relu( sum_k agg[n][k]*Wl[j][k] + h[n][k]*Wr[j][k] + b[j], 0.5 )
// MFMA 16x16x32 bf16. Block = 256 thr = 4 waves (2x2), tile 64 rows x 128 cols.
// A/H staged via coalesced uint4 into 272B-padded LDS; W is fragment-swizzled
// (conv_all) so each bw load reads one contiguous 256B chunk.
template <int OUT_F32>
__global__ __launch_bounds__(256) void sage_gemm_mfma(
    const unsigned short* __restrict__ Ab,   // [NN][128] aggregated
    const unsigned short* __restrict__ Hb,   // [NN][128] root
    const unsigned short* __restrict__ Wlb,  // swizzled [8][16][16][8]
    const unsigned short* __restrict__ Wrb,
    const float* __restrict__ bias,
    float* __restrict__ outf,
    unsigned short* __restrict__ outb)
{
    __shared__ unsigned short sA[64][136];   // 17.4 KB (272B rows)
    __shared__ unsigned short sH[64][136];
    const int tid = threadIdx.x;
    const int block0 = blockIdx.x * 64;

    {
        int i = tid;   // 64 rows x 16 quads = 1024; 4 iters of 256 threads
#pragma unroll
        for (int k = 0; k < 4; ++k, i += 256) {
            int row = i >> 4, c16 = i & 15;
            int grow = block0 + row; if (grow >= NN) grow = NN - 1;
            *(uint4*)(&sA[row][c16 * 8]) = *(const uint4*)(Ab + (size_t)grow * D + c16 * 8);
            *(uint4*)(&sH[row][c16 * 8]) = *(const uint4*)(Hb + (size_t)grow * D + c16 * 8);
        }
    }
    __syncthreads();

    const int lane = tid & 63;
    const int wid  = tid >> 6;
    const int r  = lane & 15;
    const int kg = lane >> 4;
    const int rbase = (wid >> 1) * 32;     // 0 or 32
    const int col0  = (wid & 1) * 64;
    const int jb0   = col0 >> 4;

    float bv[4];
#pragma unroll
    for (int c = 0; c < 4; ++c) bv[c] = bias[col0 + c * 16 + r];

    f32x4 acc[2][4];
#pragma unroll
    for (int m = 0; m < 2; ++m)
#pragma unroll
        for (int c = 0; c < 4; ++c) acc[m][c] = (f32x4){0.f, 0.f, 0.f, 0.f};

#pragma unroll
    for (int ks = 0; ks < 8; ++ks) {
        const unsigned short (*S)[136] = (ks < 4) ? sA : sH;
        const unsigned short* W = (ks < 4) ? Wlb : Wrb;
        const int kk = (ks & 3) * 32 + kg * 8;
        const int kb = (ks & 3) * 4 + kg;
        bf16x8 a0 = *(const bf16x8*)(&S[rbase + r][kk]);
        bf16x8 a1 = *(const bf16x8*)(&S[rbase + 16 + r][kk]);
        bf16x8 bw[4];
#pragma unroll
        for (int c = 0; c < 4; ++c)
            bw[c] = *(const bf16x8*)(W + (((jb0 + c) * 16 + kb) * 16 + r) * 8);
#pragma unroll
        for (int c = 0; c < 4; ++c) {
            acc[0][c] = __builtin_amdgcn_mfma_f32_16x16x32_bf16(a0, bw[c], acc[0][c], 0, 0, 0);
            acc[1][c] = __builtin_amdgcn_mfma_f32_16x16x32_bf16(a1, bw[c], acc[1][c], 0, 0, 0);
        }
    }

    // C/D layout: col = c*16 + (lane&15), row = m*16 + (lane>>4)*4 + q   [m89]
#pragma unroll
    for (int m = 0; m < 2; ++m) {
#pragma unroll
        for (int q = 0; q < 4; ++q) {
            int row = block0 + rbase + m * 16 + kg * 4 + q;
            if (row < NN) {
#pragma unroll
                for (int c = 0; c < 4; ++c) {
                    float v = acc[m][c][q] + bv[c];
                    v = v > 0.f ? v : 0.5f * v;
                    int colj = col0 + c * 16 + r;
                    if (OUT_F32) outf[(size_t)row * D + colj] = v;
                    else         outb[(size_t)row * D + colj] = f2b(v);
                }
            }
        }
    }
}

extern "C" void kernel_launch(void* const* d_in, const int* in_sizes, int n_in,
                              void* d_out, int out_size, void* d_ws, size_t ws_size,
                              hipStream_t stream) {
    const float* x   = (const float*)d_in[0];
    const int*   ei  = (const int*)d_in[1];
    const float* W1l = (const float*)d_in[2];
    const float* W1r = (const float*)d_in[3];
    const float* b1  = (const float*)d_in[4];
    const float* W2l = (const float*)d_in[5];
    const float* W2r = (const float*)d_in[6];
    const float* b2  = (const float*)d_in[7];
    float* out = (float*)d_out;

    char* ws = (char*)d_ws;
    size_t off = 0;
    auto alloc = [&](size_t bytes) {
        void* p = ws + off;
        off = (off + bytes + 255) & ~(size_t)255;
        return p;
    };
    int* rowbeg = (int*)alloc((size_t)NN * 4);
    int* rowend = (int*)alloc((size_t)NN * 4);
    int* gcur   = (int*)alloc((NB + 1) * 4);
    int* col    = (int*)alloc((size_t)NB * BSLOT * 4);   // gapped CSR (8 MB)
    unsigned short* xb   = (unsigned short*)alloc((size_t)NN * D * 2);
    unsigned short* aggb = (unsigned short*)alloc((size_t)NN * D * 2);
    unsigned short* h1b  = (unsigned short*)alloc((size_t)NN * D * 2);
    unsigned short* wb   = (unsigned short*)alloc((size_t)4 * D * D * 2);
    unsigned short* w1lb = wb;
    unsigned short* w1rb = wb + D * D;
    unsigned short* w2lb = wb + 2 * D * D;
    unsigned short* w2rb = wb + 3 * D * D;
    // ebuf (8 MB) aliases h1b (25.6 MB): ebuf dead before h1b is written
    unsigned* ebuf = (unsigned*)h1b;

    // ---- conversions (block 0 inits gcur; ordered before bin_scatter) ----
    const int xn4 = NN * D / 4;
    conv_all<<<(xn4 + 4 * D * D / 4 + 255) / 256, 256, 0, stream>>>(
        x, W1l, W1r, W2l, W2r, xb, wb, gcur);

    // ---- CSR build: self-sizing bucket regions, one sort block per bucket ----
    bin_scatter<<<(NE + BCHUNK - 1) / BCHUNK, 1024, 0, stream>>>(ei, gcur, ebuf);
    sort_bucket<<<NB, 512, 0, stream>>>(ebuf, gcur, rowbeg, rowend, col);

    // ---- layer 1 ----
    aggregate<<<(NN + 3) / 4, 256, 0, stream>>>(xb, rowbeg, rowend, col, aggb);
    sage_gemm_mfma<0><<<(NN + 63) / 64, 256, 0, stream>>>(aggb, xb, w1lb, w1rb, b1,
                                                          nullptr, h1b);
    // ---- layer 2 ----
    aggregate<<<(NN + 3) / 4, 256, 0, stream>>>(h1b, rowbeg, rowend, col, aggb);
    sage_gemm_mfma<1><<<(NN + 63) / 64, 256, 0, stream>>>(aggb, h1b, w2lb, w2rb, b2,
                                                          out, nullptr);
}